// Round 5
// baseline (67.685 us; speedup 1.0000x reference)
//
#include <hip/hip_runtime.h>

#define QK_SCALE 0.17677669529663687f  // 32^-0.5
#define TOKENS 9216

typedef __attribute__((ext_vector_type(8))) __bf16 bf16x8;
typedef __attribute__((ext_vector_type(8))) unsigned short us8;
typedef unsigned short us8a4 __attribute__((ext_vector_type(8), aligned(4)));
typedef __attribute__((ext_vector_type(4))) float f32x4;

static __device__ __forceinline__ unsigned short f2bf(float x) {
    unsigned int u = __float_as_uint(x);
    return (unsigned short)((u + 0x7FFFu + ((u >> 16) & 1u)) >> 16);
}
static __device__ __forceinline__ float bf2f(unsigned short u) {
    return __uint_as_float(((unsigned int)u) << 16);
}
static __device__ __forceinline__ bf16x8 ld_bf8(const unsigned short* p) {
    us8 u = *reinterpret_cast<const us8*>(p);
    return __builtin_bit_cast(bf16x8, u);
}
static __device__ __forceinline__ bf16x8 ld_bf8_a4(const unsigned short* p) {
    us8a4 u = *reinterpret_cast<const us8a4*>(p);   // 4B-aligned global load
    return __builtin_bit_cast(bf16x8, (us8)u);
}

// ---------- fused prep: x->bf16; w_qkv->bf16 T [768][256]; w_proj->bf16 T [256][256];
//            bias table 36 cls x 8 heads x [tok16][n15:16][j:16] (bf16; 0xFF80=-inf, pad j>=6 per half)
__global__ __launch_bounds__(256) void conv_prep(
    const float* __restrict__ x, const float* __restrict__ wqkv, const float* __restrict__ wproj,
    const float* __restrict__ rpb,
    unsigned short* __restrict__ xb, unsigned short* __restrict__ wqT,
    unsigned short* __restrict__ wpT, unsigned short* __restrict__ biasT)
{
    int b = blockIdx.x, t = threadIdx.x;
    if (b < 2304) {
        int idx = (b * 256 + t) * 4;
        float4 v = *reinterpret_cast<const float4*>(x + idx);
        ushort4 o;
        o.x = f2bf(v.x); o.y = f2bf(v.y); o.z = f2bf(v.z); o.w = f2bf(v.w);
        *reinterpret_cast<ushort4*>(xb + idx) = o;
    } else if (b < 3072) {
        int e = (b - 2304) * 256 + t;      // 768*256
        int n = e >> 8, k = e & 255;
        wqT[n * 256 + k] = f2bf(wqkv[k * 768 + n]);
    } else if (b < 3328) {
        int e = (b - 3072) * 256 + t;      // 256*256
        int n = e >> 8, k = e & 255;
        wpT[n * 256 + k] = f2bf(wproj[k * 256 + n]);
    } else {
        const int bid = b - 3328;          // cls*8 + h
        const int cls = bid >> 3, h = bid & 7;
        const int d  = cls / 9;
        const int r  = cls % 9;
        const int yc = r / 3, xc = r % 3;
        const int by = (yc == 0) ? 0 : ((yc == 1) ? 5 : 11);
        const int bx = (xc == 0) ? 0 : ((xc == 1) ? 5 : 11);
        const int y0 = by * 4, x0 = bx * 4;
        const int base_d = min(max(d - 1, 0), 1);
        const int base_h = min(max(y0 - 2, 0), 40);
        const int base_w = min(max(x0 - 2, 0), 40);
        const int relD = base_d - d + 2;
        unsigned short* dst = biasT + (size_t)bid * 4096;
        for (int idx = t; idx < 4096; idx += 256) {
            int tok = idx >> 8;
            int rem = idx & 255;
            int n15 = rem >> 4, j = rem & 15;
            int w = j >> 3, i = j & 7;
            unsigned short v = 0;
            if (i < 6) {
                int cand = w * 96 + i * 16 + n15;
                int y = y0 + (tok >> 2), xx = x0 + (tok & 3);
                int sh = min(max(y - 2, 0), 43), sw = min(max(xx - 2, 0), 43);
                int ld = cand >> 6, lh = (cand >> 3) & 7, lw = cand & 7;
                int t0 = lh - (sh - base_h), t1 = lw - (sw - base_w);
                bool valid = ((unsigned)t0 < 5u) && ((unsigned)t1 < 5u);
                v = 0xFF80;  // bf16 -inf
                if (valid) {
                    int bi = (relD + ld) * 81 + (lh - (y - base_h) + 4) * 9 + (lw - (xx - base_w) + 4);
                    v = f2bf(rpb[h * 405 + bi]);
                }
            }
            dst[idx] = v;
        }
    }
}

// ---------- LDS-free MFMA GEMM: C[M][N] = A[M][256] * BT[N][256]^T, K=256
// MODE 0: qkv epilogue -> q*SCALE,k as [head][token][32]; v TRANSPOSED as [head][32][token]
// MODE 1: float out + bias
template<int MF, int NF, int MODE>
__global__ __launch_bounds__(256) void gemm_mfma(
    const unsigned short* __restrict__ A, const unsigned short* __restrict__ BT,
    const float* __restrict__ bias,
    unsigned short* __restrict__ oq, unsigned short* __restrict__ ok,
    unsigned short* __restrict__ ovT, float* __restrict__ of)
{
    const int tid = threadIdx.x;
    const int wid = tid >> 6, lane = tid & 63;
    const int wm = wid >> 1, wn = wid & 1;
    const int n15 = lane & 15, g = lane >> 4;
    const int m0 = blockIdx.y * (MF * 32) + wm * (MF * 16);
    const int n0 = blockIdx.x * (NF * 32) + wn * (NF * 16);

    f32x4 acc[MF][NF];
    #pragma unroll
    for (int i = 0; i < MF; i++)
        #pragma unroll
        for (int j = 0; j < NF; j++)
            acc[i][j] = f32x4{0.f, 0.f, 0.f, 0.f};

    #pragma unroll
    for (int ks = 0; ks < 8; ++ks) {
        bf16x8 a[MF], b[NF];
        #pragma unroll
        for (int mt = 0; mt < MF; ++mt)
            a[mt] = ld_bf8(A + (size_t)(m0 + mt * 16 + n15) * 256 + ks * 32 + g * 8);
        #pragma unroll
        for (int nt = 0; nt < NF; ++nt)
            b[nt] = ld_bf8(BT + (size_t)(n0 + nt * 16 + n15) * 256 + ks * 32 + g * 8);
        #pragma unroll
        for (int mt = 0; mt < MF; ++mt)
            #pragma unroll
            for (int nt = 0; nt < NF; ++nt)
                acc[mt][nt] = __builtin_amdgcn_mfma_f32_16x16x32_bf16(a[mt], b[nt], acc[mt][nt], 0, 0, 0);
    }

    #pragma unroll
    for (int mt = 0; mt < MF; ++mt) {
        #pragma unroll
        for (int nt = 0; nt < NF; ++nt) {
            int col = n0 + nt * 16 + n15;
            float bv = bias[col];
            float v4[4];
            #pragma unroll
            for (int rg = 0; rg < 4; ++rg) v4[rg] = acc[mt][nt][rg] + bv;
            int row0 = m0 + mt * 16 + g * 4;
            if (MODE == 0) {
                int part = col >> 8, c = col & 255, hh = c >> 5, ch = c & 31;
                if (part == 2) {
                    // V^T: [head][32][token] = index c*9216 + token; 4 consecutive tokens -> ushort4
                    ushort4 o;
                    o.x = f2bf(v4[0]); o.y = f2bf(v4[1]); o.z = f2bf(v4[2]); o.w = f2bf(v4[3]);
                    *reinterpret_cast<ushort4*>(ovT + (size_t)c * TOKENS + row0) = o;
                } else {
                    unsigned short* dst = (part == 0) ? oq : ok;
                    float sc = (part == 0) ? QK_SCALE : 1.f;
                    #pragma unroll
                    for (int rg = 0; rg < 4; ++rg)
                        dst[((size_t)hh * TOKENS + row0 + rg) * 32 + ch] = f2bf(v4[rg] * sc);
                }
            } else {
                #pragma unroll
                for (int rg = 0; rg < 4; ++rg)
                    of[(size_t)(row0 + rg) * 256 + col] = v4[rg];
            }
        }
    }
}

// ---------- MFMA neighborhood attention ----------
// block: 1 head x 4x4x1 token tile (16 tokens), candidate union = 3x8x8 = 192; 2 waves.
// No V in LDS: PV B-fragments are direct 16B global loads from V^T [head][32][token]
// (8 cands aligned-by-8 = 8 contiguous tokens). Max-free softmax, deferred normalization.
__global__ __launch_bounds__(128) void nat_attn_mfma(
    const unsigned short* __restrict__ qws, const unsigned short* __restrict__ kws,
    const unsigned short* __restrict__ vTg, const unsigned short* __restrict__ biasT,
    unsigned short* __restrict__ aout)
{
    __shared__ unsigned short Pl[16 * 200];   // P~ [tok][cand], stride 200
    __shared__ float red[2][16];              // per-wave partial denominators

    const int tid = threadIdx.x;
    const int w = tid >> 6, lane = tid & 63;
    const int n15 = lane & 15, g = lane >> 4;

    int b = blockIdx.x;
    const int h = b & 7; b >>= 3;
    const int bx = b % 12; b /= 12;
    const int by = b % 12;
    const int d  = b / 12;
    const int y0 = by * 4, x0 = bx * 4;
    const int base_d = min(max(d - 1, 0), 1);
    const int base_h = min(max(y0 - 2, 0), 40);
    const int base_w = min(max(x0 - 2, 0), 40);

    const int yc = (by == 0) ? 0 : ((by == 11) ? 2 : 1);
    const int xc = (bx == 0) ? 0 : ((bx == 11) ? 2 : 1);
    const unsigned short* bT = biasT + (size_t)(((d * 9 + yc * 3 + xc) * 8 + h)) * 4096;

    const size_t hoff = (size_t)h * TOKENS * 32;
    const unsigned short* kb = kws + hoff;
    const unsigned short* qb = qws + hoff;

    // ---- bias loads: one us8 per rg (16B, elements w*8+i, i<6 used) ----
    float bvv[6][4];
    #pragma unroll
    for (int rg = 0; rg < 4; ++rg) {
        us8 bl = *reinterpret_cast<const us8*>(bT + (size_t)(((g * 4 + rg) * 16 + n15) * 16 + w * 8));
        #pragma unroll
        for (int i = 0; i < 6; ++i) bvv[i][rg] = bf2f(bl[i]);
    }

    // ---- QK^T ----
    const int gtq = d * 2304 + (y0 + (n15 >> 2)) * 48 + (x0 + (n15 & 3));
    bf16x8 qf = ld_bf8(qb + (size_t)gtq * 32 + g * 8);

    f32x4 sf[6];
    #pragma unroll
    for (int i = 0; i < 6; ++i) {
        int cand = (w * 6 + i) * 16 + n15;
        int ld = cand >> 6, lh = (cand >> 3) & 7, lw = cand & 7;
        int gtc = (base_d + ld) * 2304 + (base_h + lh) * 48 + (base_w + lw);
        bf16x8 kf = ld_bf8(kb + (size_t)gtc * 32 + g * 8);
        sf[i] = __builtin_amdgcn_mfma_f32_16x16x32_bf16(qf, kf, f32x4{0.f, 0.f, 0.f, 0.f}, 0, 0, 0);
    }

    // ---- PV B-operand global loads issued early (latency hides under softmax) ----
    bf16x8 vf[6];
    const unsigned short* vrowbase = vTg + (size_t)(h * 32 + w * 16 + n15) * TOKENS;
    #pragma unroll
    for (int ks = 0; ks < 6; ++ks) {
        int cand0 = ks * 32 + g * 8;           // aligned-by-8 -> one contiguous 8-token run
        int ld = cand0 >> 6, lh = (cand0 >> 3) & 7;
        vf[ks] = ld_bf8_a4(vrowbase + (base_d + ld) * 2304 + (base_h + lh) * 48 + base_w);
    }

    // ---- max-free softmax: P~ = exp(s+b), per-wave sum over 16 lanes ----
    float psum[4];
    unsigned short pw[4][6];
    #pragma unroll
    for (int rg = 0; rg < 4; ++rg) {
        float e[6];
        #pragma unroll
        for (int i = 0; i < 6; ++i)
            e[i] = __expf(sf[i][rg] + bvv[i][rg]);   // invalid -> exp(-inf)=0
        float s = ((e[0] + e[1]) + (e[2] + e[3])) + (e[4] + e[5]);
        #pragma unroll
        for (int msk = 1; msk < 16; msk <<= 1) s += __shfl_xor(s, msk);
        psum[rg] = s;
        #pragma unroll
        for (int i = 0; i < 6; ++i) pw[rg][i] = f2bf(e[i]);
    }

    #pragma unroll
    for (int rg = 0; rg < 4; ++rg)
        #pragma unroll
        for (int i = 0; i < 6; ++i)
            Pl[(g * 4 + rg) * 200 + (w * 96 + i * 16 + n15)] = pw[rg][i];
    if (n15 == 0) {
        #pragma unroll
        for (int rg = 0; rg < 4; ++rg) red[w][g * 4 + rg] = psum[rg];
    }
    __syncthreads();

    // ---- PV (unnormalized), normalize in epilogue ----
    f32x4 oacc = f32x4{0.f, 0.f, 0.f, 0.f};
    #pragma unroll
    for (int ks = 0; ks < 6; ++ks) {
        bf16x8 pa = ld_bf8(&Pl[n15 * 200 + ks * 32 + g * 8]);
        oacc = __builtin_amdgcn_mfma_f32_16x16x32_bf16(pa, vf[ks], oacc, 0, 0, 0);
    }
    #pragma unroll
    for (int rg = 0; rg < 4; ++rg) {
        int tok = g * 4 + rg;
        float inv = 1.f / (red[0][tok] + red[1][tok]);
        int gtr = d * 2304 + (y0 + (tok >> 2)) * 48 + (x0 + (tok & 3));
        aout[(size_t)gtr * 256 + h * 32 + w * 16 + n15] = f2bf(oacc[rg] * inv);
    }
}

extern "C" void kernel_launch(void* const* d_in, const int* in_sizes, int n_in,
                              void* d_out, int out_size, void* d_ws, size_t ws_size,
                              hipStream_t stream) {
    const float* x      = (const float*)d_in[0];
    const float* w_qkv  = (const float*)d_in[1];
    const float* b_qkv  = (const float*)d_in[2];
    const float* rpb    = (const float*)d_in[3];
    const float* w_proj = (const float*)d_in[4];
    const float* b_proj = (const float*)d_in[5];
    float* out = (float*)d_out;

    unsigned short* ws = (unsigned short*)d_ws;
    unsigned short* xb    = ws;                       // 2359296
    unsigned short* wqT   = ws + (size_t)2359296;     // 196608
    unsigned short* wpT   = ws + (size_t)2555904;     // 65536
    unsigned short* qws   = ws + (size_t)2621440;     // 2359296
    unsigned short* kws   = ws + (size_t)4980736;     // 2359296
    unsigned short* vTg   = ws + (size_t)7340032;     // 2359296  (V^T [head][32][token])
    unsigned short* aws   = ws + (size_t)9699328;     // 2359296
    unsigned short* biasT = ws + (size_t)12058624;    // 1179648

    conv_prep<<<dim3(3616), 256, 0, stream>>>(x, w_qkv, w_proj, rpb, xb, wqT, wpT, biasT);

    // QKV: [9216,256] x [256,768] ; block tile 128x128
    gemm_mfma<4, 4, 0><<<dim3(6, 72), 256, 0, stream>>>(xb, wqT, b_qkv, qws, kws, vTg, nullptr);

    nat_attn_mfma<<<dim3(4608), 128, 0, stream>>>(qws, kws, vTg, biasT, aws);

    // proj: [9216,256] x [256,256] ; block tile 64x64
    gemm_mfma<2, 2, 1><<<dim3(4, 144), 256, 0, stream>>>(aws, wpT, b_proj, nullptr, nullptr, nullptr, out);
}

// Round 6
// 66.250 us; speedup vs baseline: 1.0216x; 1.0216x over previous
//
#include <hip/hip_runtime.h>

#define QK_SCALE 0.17677669529663687f  // 32^-0.5
#define TOKENS 9216

typedef __attribute__((ext_vector_type(8))) __bf16 bf16x8;
typedef __attribute__((ext_vector_type(8))) unsigned short us8;
typedef __attribute__((ext_vector_type(4))) float f32x4;

static __device__ __forceinline__ unsigned short f2bf(float x) {
    unsigned int u = __float_as_uint(x);
    return (unsigned short)((u + 0x7FFFu + ((u >> 16) & 1u)) >> 16);
}
static __device__ __forceinline__ float bf2f(unsigned short u) {
    return __uint_as_float(((unsigned int)u) << 16);
}
static __device__ __forceinline__ bf16x8 ld_bf8(const unsigned short* p) {
    us8 u = *reinterpret_cast<const us8*>(p);
    return __builtin_bit_cast(bf16x8, u);
}

// ---------- fused prep: x->bf16; w_qkv->bf16 T [768][256]; w_proj->bf16 T [256][256];
//            bias table 36 cls x 8 heads x [tok:16][w:2][g:4][j:24], j=i*4+rg -> cand=w*96+i*16+g*4+rg
__global__ __launch_bounds__(256) void conv_prep(
    const float* __restrict__ x, const float* __restrict__ wqkv, const float* __restrict__ wproj,
    const float* __restrict__ rpb,
    unsigned short* __restrict__ xb, unsigned short* __restrict__ wqT,
    unsigned short* __restrict__ wpT, unsigned short* __restrict__ biasT)
{
    int b = blockIdx.x, t = threadIdx.x;
    if (b < 2304) {
        int idx = (b * 256 + t) * 4;
        float4 v = *reinterpret_cast<const float4*>(x + idx);
        ushort4 o;
        o.x = f2bf(v.x); o.y = f2bf(v.y); o.z = f2bf(v.z); o.w = f2bf(v.w);
        *reinterpret_cast<ushort4*>(xb + idx) = o;
    } else if (b < 3072) {
        int e = (b - 2304) * 256 + t;      // 768*256
        int n = e >> 8, k = e & 255;
        wqT[n * 256 + k] = f2bf(wqkv[k * 768 + n]);
    } else if (b < 3328) {
        int e = (b - 3072) * 256 + t;      // 256*256
        int n = e >> 8, k = e & 255;
        wpT[n * 256 + k] = f2bf(wproj[k * 256 + n]);
    } else {
        const int bid = b - 3328;          // cls*8 + h
        const int cls = bid >> 3, h = bid & 7;
        const int d  = cls / 9;
        const int r  = cls % 9;
        const int yc = r / 3, xc = r % 3;
        const int by = (yc == 0) ? 0 : ((yc == 1) ? 5 : 11);
        const int bx = (xc == 0) ? 0 : ((xc == 1) ? 5 : 11);
        const int y0 = by * 4, x0 = bx * 4;
        const int base_d = min(max(d - 1, 0), 1);
        const int base_h = min(max(y0 - 2, 0), 40);
        const int base_w = min(max(x0 - 2, 0), 40);
        const int relD = base_d - d + 2;
        unsigned short* dst = biasT + (size_t)bid * 3072;
        for (int idx = t; idx < 3072; idx += 256) {
            // idx = ((tok*2 + w)*4 + g)*24 + j ; j = i*4 + rg
            int tok = idx / 192;
            int rem = idx - tok * 192;
            int w = rem / 96; rem -= w * 96;
            int g = rem / 24;
            int j = rem - g * 24;
            int i = j >> 2, rg = j & 3;
            int cand = w * 96 + i * 16 + g * 4 + rg;
            int y = y0 + (tok >> 2), xx = x0 + (tok & 3);
            int sh = min(max(y - 2, 0), 43), sw = min(max(xx - 2, 0), 43);
            int ld = cand >> 6, lh = (cand >> 3) & 7, lw = cand & 7;
            int t0 = lh - (sh - base_h), t1 = lw - (sw - base_w);
            bool valid = ((unsigned)t0 < 5u) && ((unsigned)t1 < 5u);
            unsigned short v = 0xFF80;  // bf16 -inf
            if (valid) {
                int bi = (relD + ld) * 81 + (lh - (y - base_h) + 4) * 9 + (lw - (xx - base_w) + 4);
                v = f2bf(rpb[h * 405 + bi]);
            }
            dst[idx] = v;
        }
    }
}

// ---------- LDS-free MFMA GEMM: C[M][N] = A[M][256] * BT[N][256]^T, K=256
template<int MF, int NF, int MODE>
__global__ __launch_bounds__(256) void gemm_mfma(
    const unsigned short* __restrict__ A, const unsigned short* __restrict__ BT,
    const float* __restrict__ bias,
    unsigned short* __restrict__ oq, unsigned short* __restrict__ ok,
    unsigned short* __restrict__ ov, float* __restrict__ of)
{
    const int tid = threadIdx.x;
    const int wid = tid >> 6, lane = tid & 63;
    const int wm = wid >> 1, wn = wid & 1;
    const int n15 = lane & 15, g = lane >> 4;
    const int m0 = blockIdx.y * (MF * 32) + wm * (MF * 16);
    const int n0 = blockIdx.x * (NF * 32) + wn * (NF * 16);

    f32x4 acc[MF][NF];
    #pragma unroll
    for (int i = 0; i < MF; i++)
        #pragma unroll
        for (int j = 0; j < NF; j++)
            acc[i][j] = f32x4{0.f, 0.f, 0.f, 0.f};

    #pragma unroll
    for (int ks = 0; ks < 8; ++ks) {
        bf16x8 a[MF], b[NF];
        #pragma unroll
        for (int mt = 0; mt < MF; ++mt)
            a[mt] = ld_bf8(A + (size_t)(m0 + mt * 16 + n15) * 256 + ks * 32 + g * 8);
        #pragma unroll
        for (int nt = 0; nt < NF; ++nt)
            b[nt] = ld_bf8(BT + (size_t)(n0 + nt * 16 + n15) * 256 + ks * 32 + g * 8);
        #pragma unroll
        for (int mt = 0; mt < MF; ++mt)
            #pragma unroll
            for (int nt = 0; nt < NF; ++nt)
                acc[mt][nt] = __builtin_amdgcn_mfma_f32_16x16x32_bf16(a[mt], b[nt], acc[mt][nt], 0, 0, 0);
    }

    #pragma unroll
    for (int mt = 0; mt < MF; ++mt) {
        #pragma unroll
        for (int nt = 0; nt < NF; ++nt) {
            int col = n0 + nt * 16 + n15;
            float bv = bias[col];
            #pragma unroll
            for (int rg = 0; rg < 4; ++rg) {
                int row = m0 + mt * 16 + g * 4 + rg;
                float val = acc[mt][nt][rg] + bv;
                if (MODE == 0) {
                    int part = col >> 8, c = col & 255, hh = c >> 5, ch = c & 31;
                    unsigned short* dst = (part == 0) ? oq : ((part == 1) ? ok : ov);
                    if (part == 0) val *= QK_SCALE;
                    dst[((size_t)hh * TOKENS + row) * 32 + ch] = f2bf(val);
                } else {
                    of[(size_t)row * 256 + col] = val;
                }
            }
        }
    }
}

// ---------- MFMA neighborhood attention ----------
// block: 1 head x 4x4x1 token tile (16 tokens), candidate union = 3x8x8 = 192; 2 waves.
// Swapped QK^T: mfma(K,Q) -> lane n15 = token, regs = 24 cands. Max-free softmax fully
// in-lane (2 shuffles), P~ written as 6x ds_write_b64. Normalization deferred to epilogue.
__global__ __launch_bounds__(128) void nat_attn_mfma(
    const unsigned short* __restrict__ qws, const unsigned short* __restrict__ kws,
    const unsigned short* __restrict__ vws, const unsigned short* __restrict__ biasT,
    unsigned short* __restrict__ aout)
{
    __shared__ unsigned short VT[32 * 200];   // V^T [ch][cand], stride 200
    __shared__ unsigned short Pl[16 * 200];   // P~  [tok][cand], stride 200
    __shared__ float red[2][16];              // per-wave partial denominators

    const int tid = threadIdx.x;
    const int w = tid >> 6, lane = tid & 63;
    const int n15 = lane & 15, g = lane >> 4;

    int b = blockIdx.x;
    const int h = b & 7; b >>= 3;
    const int bx = b % 12; b /= 12;
    const int by = b % 12;
    const int d  = b / 12;
    const int y0 = by * 4, x0 = bx * 4;
    const int base_d = min(max(d - 1, 0), 1);
    const int base_h = min(max(y0 - 2, 0), 40);
    const int base_w = min(max(x0 - 2, 0), 40);

    const int yc = (by == 0) ? 0 : ((by == 11) ? 2 : 1);
    const int xc = (bx == 0) ? 0 : ((bx == 11) ? 2 : 1);
    const unsigned short* bT = biasT + (size_t)(((d * 9 + yc * 3 + xc) * 8 + h)) * 3072;

    const size_t hoff = (size_t)h * TOKENS * 32;
    const unsigned short* kb = kws + hoff;
    const unsigned short* vb = vws + hoff;
    const unsigned short* qb = qws + hoff;

    // ---- stage V^T (coalesced global reads, scalar LDS transpose writes) ----
    for (int id = tid; id < 768; id += 128) {
        int cand = id % 192, chg = id / 192;
        int ld = cand >> 6, lh = (cand >> 3) & 7, lw = cand & 7;
        int gt = (base_d + ld) * 2304 + (base_h + lh) * 48 + (base_w + lw);
        us8 u = *reinterpret_cast<const us8*>(vb + (size_t)gt * 32 + chg * 8);
        #pragma unroll
        for (int e = 0; e < 8; e++) VT[(chg * 8 + e) * 200 + cand] = u[e];
    }

    // ---- bias loads: 24 contiguous bf16 per lane = 3 x us8 ----
    us8 bl[3];
    {
        const unsigned short* bp = bT + (size_t)(((n15 * 2 + w) * 4 + g) * 24);
        bl[0] = *reinterpret_cast<const us8*>(bp);
        bl[1] = *reinterpret_cast<const us8*>(bp + 8);
        bl[2] = *reinterpret_cast<const us8*>(bp + 16);
    }

    // ---- QK^T (swapped: A=K, B=Q) -> D[cand][tok], lane n15 = token ----
    const int gtq = d * 2304 + (y0 + (n15 >> 2)) * 48 + (x0 + (n15 & 3));
    bf16x8 qf = ld_bf8(qb + (size_t)gtq * 32 + g * 8);

    f32x4 sf[6];
    #pragma unroll
    for (int i = 0; i < 6; ++i) {
        int cand = (w * 6 + i) * 16 + n15;
        int ld = cand >> 6, lh = (cand >> 3) & 7, lw = cand & 7;
        int gtc = (base_d + ld) * 2304 + (base_h + lh) * 48 + (base_w + lw);
        bf16x8 kf = ld_bf8(kb + (size_t)gtc * 32 + g * 8);
        sf[i] = __builtin_amdgcn_mfma_f32_16x16x32_bf16(kf, qf, f32x4{0.f, 0.f, 0.f, 0.f}, 0, 0, 0);
    }

    // ---- max-free softmax, fully in-lane; cand = w*96 + i*16 + g*4 + rg, tok = n15 ----
    float s24 = 0.f;
    ushort4 pq[6];
    #pragma unroll
    for (int i = 0; i < 6; ++i) {
        float e0, e1, e2, e3;
        {
            int j = i * 4;
            e0 = __expf(sf[i][0] + bf2f(bl[(j + 0) >> 3][(j + 0) & 7]));
            e1 = __expf(sf[i][1] + bf2f(bl[(j + 1) >> 3][(j + 1) & 7]));
            e2 = __expf(sf[i][2] + bf2f(bl[(j + 2) >> 3][(j + 2) & 7]));
            e3 = __expf(sf[i][3] + bf2f(bl[(j + 3) >> 3][(j + 3) & 7]));
        }
        s24 += (e0 + e1) + (e2 + e3);
        pq[i].x = f2bf(e0); pq[i].y = f2bf(e1); pq[i].z = f2bf(e2); pq[i].w = f2bf(e3);
    }
    s24 += __shfl_xor(s24, 16);
    s24 += __shfl_xor(s24, 32);
    if (g == 0) red[w][n15] = s24;

    #pragma unroll
    for (int i = 0; i < 6; ++i)
        *reinterpret_cast<ushort4*>(&Pl[n15 * 200 + w * 96 + i * 16 + g * 4]) = pq[i];
    __syncthreads();

    // ---- PV (unnormalized), normalize in epilogue ----
    f32x4 oacc = f32x4{0.f, 0.f, 0.f, 0.f};
    #pragma unroll
    for (int ks = 0; ks < 6; ++ks) {
        bf16x8 pa = ld_bf8(&Pl[n15 * 200 + ks * 32 + g * 8]);
        bf16x8 vf = ld_bf8(&VT[(w * 16 + n15) * 200 + ks * 32 + g * 8]);
        oacc = __builtin_amdgcn_mfma_f32_16x16x32_bf16(pa, vf, oacc, 0, 0, 0);
    }
    #pragma unroll
    for (int rg = 0; rg < 4; ++rg) {
        int tok = g * 4 + rg;
        float inv = 1.f / (red[0][tok] + red[1][tok]);
        int gtr = d * 2304 + (y0 + (tok >> 2)) * 48 + (x0 + (tok & 3));
        aout[(size_t)gtr * 256 + h * 32 + w * 16 + n15] = f2bf(oacc[rg] * inv);
    }
}

extern "C" void kernel_launch(void* const* d_in, const int* in_sizes, int n_in,
                              void* d_out, int out_size, void* d_ws, size_t ws_size,
                              hipStream_t stream) {
    const float* x      = (const float*)d_in[0];
    const float* w_qkv  = (const float*)d_in[1];
    const float* b_qkv  = (const float*)d_in[2];
    const float* rpb    = (const float*)d_in[3];
    const float* w_proj = (const float*)d_in[4];
    const float* b_proj = (const float*)d_in[5];
    float* out = (float*)d_out;

    unsigned short* ws = (unsigned short*)d_ws;
    unsigned short* xb    = ws;                       // 2359296
    unsigned short* wqT   = ws + (size_t)2359296;     // 196608
    unsigned short* wpT   = ws + (size_t)2555904;     // 65536
    unsigned short* qws   = ws + (size_t)2621440;     // 2359296
    unsigned short* kws   = ws + (size_t)4980736;     // 2359296
    unsigned short* vws   = ws + (size_t)7340032;     // 2359296
    unsigned short* aws   = ws + (size_t)9699328;     // 2359296
    unsigned short* biasT = ws + (size_t)12058624;    // 884736

    conv_prep<<<dim3(3616), 256, 0, stream>>>(x, w_qkv, w_proj, rpb, xb, wqT, wpT, biasT);

    // QKV: [9216,256] x [256,768] ; block tile 128x128
    gemm_mfma<4, 4, 0><<<dim3(6, 72), 256, 0, stream>>>(xb, wqT, b_qkv, qws, kws, vws, nullptr);

    nat_attn_mfma<<<dim3(4608), 128, 0, stream>>>(qws, kws, vws, biasT, aws);

    // proj: [9216,256] x [256,256] ; block tile 64x64
    gemm_mfma<2, 2, 1><<<dim3(4, 144), 256, 0, stream>>>(aws, wpT, b_proj, nullptr, nullptr, nullptr, out);
}

// Round 9
// 65.686 us; speedup vs baseline: 1.0304x; 1.0086x over previous
//
#include <hip/hip_runtime.h>

#define QK_SCALE 0.17677669529663687f  // 32^-0.5
#define TOKENS 9216

typedef __attribute__((ext_vector_type(8))) __bf16 bf16x8;
typedef __attribute__((ext_vector_type(8))) unsigned short us8;
typedef __attribute__((ext_vector_type(4))) float f32x4;

static __device__ __forceinline__ unsigned short f2bf(float x) {
    unsigned int u = __float_as_uint(x);
    return (unsigned short)((u + 0x7FFFu + ((u >> 16) & 1u)) >> 16);
}
static __device__ __forceinline__ float bf2f(unsigned short u) {
    return __uint_as_float(((unsigned int)u) << 16);
}
static __device__ __forceinline__ bf16x8 ld_bf8(const unsigned short* p) {
    us8 u = *reinterpret_cast<const us8*>(p);
    return __builtin_bit_cast(bf16x8, u);
}

// ---------- fused prep: x->bf16; w_qkv->bf16 T [768][256]; w_proj->bf16 T [256][256];
//            bias table 36 cls x 8 heads x [tok:16][w:2][g:4][j:24], j=i*4+rg -> cand=w*96+i*16+g*4+rg
__global__ __launch_bounds__(256) void conv_prep(
    const float* __restrict__ x, const float* __restrict__ wqkv, const float* __restrict__ wproj,
    const float* __restrict__ rpb,
    unsigned short* __restrict__ xb, unsigned short* __restrict__ wqT,
    unsigned short* __restrict__ wpT, unsigned short* __restrict__ biasT)
{
    int b = blockIdx.x, t = threadIdx.x;
    if (b < 2304) {
        int idx = (b * 256 + t) * 4;
        float4 v = *reinterpret_cast<const float4*>(x + idx);
        ushort4 o;
        o.x = f2bf(v.x); o.y = f2bf(v.y); o.z = f2bf(v.z); o.w = f2bf(v.w);
        *reinterpret_cast<ushort4*>(xb + idx) = o;
    } else if (b < 3072) {
        int e = (b - 2304) * 256 + t;      // 768*256
        int n = e >> 8, k = e & 255;
        wqT[n * 256 + k] = f2bf(wqkv[k * 768 + n]);
    } else if (b < 3328) {
        int e = (b - 3072) * 256 + t;      // 256*256
        int n = e >> 8, k = e & 255;
        wpT[n * 256 + k] = f2bf(wproj[k * 256 + n]);
    } else {
        const int bid = b - 3328;          // cls*8 + h
        const int cls = bid >> 3, h = bid & 7;
        const int d  = cls / 9;
        const int r  = cls % 9;
        const int yc = r / 3, xc = r % 3;
        const int by = (yc == 0) ? 0 : ((yc == 1) ? 5 : 11);
        const int bx = (xc == 0) ? 0 : ((xc == 1) ? 5 : 11);
        const int y0 = by * 4, x0 = bx * 4;
        const int base_d = min(max(d - 1, 0), 1);
        const int base_h = min(max(y0 - 2, 0), 40);
        const int base_w = min(max(x0 - 2, 0), 40);
        const int relD = base_d - d + 2;
        unsigned short* dst = biasT + (size_t)bid * 3072;
        for (int idx = t; idx < 3072; idx += 256) {
            // idx = ((tok*2 + w)*4 + g)*24 + j ; j = i*4 + rg
            int tok = idx / 192;
            int rem = idx - tok * 192;
            int w = rem / 96; rem -= w * 96;
            int g = rem / 24;
            int j = rem - g * 24;
            int i = j >> 2, rg = j & 3;
            int cand = w * 96 + i * 16 + g * 4 + rg;
            int y = y0 + (tok >> 2), xx = x0 + (tok & 3);
            int sh = min(max(y - 2, 0), 43), sw = min(max(xx - 2, 0), 43);
            int ld = cand >> 6, lh = (cand >> 3) & 7, lw = cand & 7;
            int t0 = lh - (sh - base_h), t1 = lw - (sw - base_w);
            bool valid = ((unsigned)t0 < 5u) && ((unsigned)t1 < 5u);
            unsigned short v = 0xFF80;  // bf16 -inf
            if (valid) {
                int bi = (relD + ld) * 81 + (lh - (y - base_h) + 4) * 9 + (lw - (xx - base_w) + 4);
                v = f2bf(rpb[h * 405 + bi]);
            }
            dst[idx] = v;
        }
    }
}

// ---------- LDS-free MFMA GEMM: C[M][N] = A[M][256] * BT[N][256]^T, K=256
template<int MF, int NF, int MODE>
__global__ __launch_bounds__(256) void gemm_mfma(
    const unsigned short* __restrict__ A, const unsigned short* __restrict__ BT,
    const float* __restrict__ bias,
    unsigned short* __restrict__ oq, unsigned short* __restrict__ ok,
    unsigned short* __restrict__ ov, float* __restrict__ of)
{
    const int tid = threadIdx.x;
    const int wid = tid >> 6, lane = tid & 63;
    const int wm = wid >> 1, wn = wid & 1;
    const int n15 = lane & 15, g = lane >> 4;
    const int m0 = blockIdx.y * (MF * 32) + wm * (MF * 16);
    const int n0 = blockIdx.x * (NF * 32) + wn * (NF * 16);

    f32x4 acc[MF][NF];
    #pragma unroll
    for (int i = 0; i < MF; i++)
        #pragma unroll
        for (int j = 0; j < NF; j++)
            acc[i][j] = f32x4{0.f, 0.f, 0.f, 0.f};

    #pragma unroll
    for (int ks = 0; ks < 8; ++ks) {
        bf16x8 a[MF], b[NF];
        #pragma unroll
        for (int mt = 0; mt < MF; ++mt)
            a[mt] = ld_bf8(A + (size_t)(m0 + mt * 16 + n15) * 256 + ks * 32 + g * 8);
        #pragma unroll
        for (int nt = 0; nt < NF; ++nt)
            b[nt] = ld_bf8(BT + (size_t)(n0 + nt * 16 + n15) * 256 + ks * 32 + g * 8);
        #pragma unroll
        for (int mt = 0; mt < MF; ++mt)
            #pragma unroll
            for (int nt = 0; nt < NF; ++nt)
                acc[mt][nt] = __builtin_amdgcn_mfma_f32_16x16x32_bf16(a[mt], b[nt], acc[mt][nt], 0, 0, 0);
    }

    #pragma unroll
    for (int mt = 0; mt < MF; ++mt) {
        #pragma unroll
        for (int nt = 0; nt < NF; ++nt) {
            int col = n0 + nt * 16 + n15;
            float bv = bias[col];
            #pragma unroll
            for (int rg = 0; rg < 4; ++rg) {
                int row = m0 + mt * 16 + g * 4 + rg;
                float val = acc[mt][nt][rg] + bv;
                if (MODE == 0) {
                    int part = col >> 8, c = col & 255, hh = c >> 5, ch = c & 31;
                    unsigned short* dst = (part == 0) ? oq : ((part == 1) ? ok : ov);
                    if (part == 0) val *= QK_SCALE;
                    dst[((size_t)hh * TOKENS + row) * 32 + ch] = f2bf(val);
                } else {
                    of[(size_t)row * 256 + col] = val;
                }
            }
        }
    }
}

// ---------- MFMA neighborhood attention ----------
// block: 1 head x 4x4x1 token tile (16 tokens), candidate union = 3x8x8 = 192; 2 waves.
// Swapped QK^T: mfma(K,Q) -> lane n15 = token, regs = 24 cands. Max-free softmax fully
// in-lane (2 shuffles), P~ via ds_write_b64. PV also swapped: mfma(V^T, P) -> D[ch][tok],
// one reciprocal + one ushort4 store per thread. Normalization deferred to epilogue.
__global__ __launch_bounds__(128) void nat_attn_mfma(
    const unsigned short* __restrict__ qws, const unsigned short* __restrict__ kws,
    const unsigned short* __restrict__ vws, const unsigned short* __restrict__ biasT,
    unsigned short* __restrict__ aout)
{
    __shared__ unsigned short VT[32 * 200];   // V^T [ch][cand], stride 200
    __shared__ unsigned short Pl[16 * 200];   // P~  [tok][cand], stride 200
    __shared__ float red[2][16];              // per-wave partial denominators

    const int tid = threadIdx.x;
    const int w = tid >> 6, lane = tid & 63;
    const int n15 = lane & 15, g = lane >> 4;

    int b = blockIdx.x;
    const int h = b & 7; b >>= 3;
    const int bx = b % 12; b /= 12;
    const int by = b % 12;
    const int d  = b / 12;
    const int y0 = by * 4, x0 = bx * 4;
    const int base_d = min(max(d - 1, 0), 1);
    const int base_h = min(max(y0 - 2, 0), 40);
    const int base_w = min(max(x0 - 2, 0), 40);

    const int yc = (by == 0) ? 0 : ((by == 11) ? 2 : 1);
    const int xc = (bx == 0) ? 0 : ((bx == 11) ? 2 : 1);
    const unsigned short* bT = biasT + (size_t)(((d * 9 + yc * 3 + xc) * 8 + h)) * 3072;

    const size_t hoff = (size_t)h * TOKENS * 32;
    const unsigned short* kb = kws + hoff;
    const unsigned short* vb = vws + hoff;
    const unsigned short* qb = qws + hoff;

    // ---- stage V^T (coalesced global reads, scalar LDS transpose writes) ----
    for (int id = tid; id < 768; id += 128) {
        int cand = id % 192, chg = id / 192;
        int ld = cand >> 6, lh = (cand >> 3) & 7, lw = cand & 7;
        int gt = (base_d + ld) * 2304 + (base_h + lh) * 48 + (base_w + lw);
        us8 u = *reinterpret_cast<const us8*>(vb + (size_t)gt * 32 + chg * 8);
        #pragma unroll
        for (int e = 0; e < 8; e++) VT[(chg * 8 + e) * 200 + cand] = u[e];
    }

    // ---- bias loads: 24 contiguous bf16 per lane = 3 x us8 ----
    us8 bl[3];
    {
        const unsigned short* bp = bT + (size_t)(((n15 * 2 + w) * 4 + g) * 24);
        bl[0] = *reinterpret_cast<const us8*>(bp);
        bl[1] = *reinterpret_cast<const us8*>(bp + 8);
        bl[2] = *reinterpret_cast<const us8*>(bp + 16);
    }

    // ---- QK^T (swapped: A=K, B=Q) -> D[cand][tok], lane n15 = token ----
    const int gtq = d * 2304 + (y0 + (n15 >> 2)) * 48 + (x0 + (n15 & 3));
    bf16x8 qf = ld_bf8(qb + (size_t)gtq * 32 + g * 8);

    f32x4 sf[6];
    #pragma unroll
    for (int i = 0; i < 6; ++i) {
        int cand = (w * 6 + i) * 16 + n15;
        int ld = cand >> 6, lh = (cand >> 3) & 7, lw = cand & 7;
        int gtc = (base_d + ld) * 2304 + (base_h + lh) * 48 + (base_w + lw);
        bf16x8 kf = ld_bf8(kb + (size_t)gtc * 32 + g * 8);
        sf[i] = __builtin_amdgcn_mfma_f32_16x16x32_bf16(kf, qf, f32x4{0.f, 0.f, 0.f, 0.f}, 0, 0, 0);
    }

    // ---- max-free softmax, fully in-lane; cand = w*96 + i*16 + g*4 + rg, tok = n15 ----
    float s24 = 0.f;
    ushort4 pq[6];
    #pragma unroll
    for (int i = 0; i < 6; ++i) {
        int j = i * 4;
        float e0 = __expf(sf[i][0] + bf2f(bl[(j + 0) >> 3][(j + 0) & 7]));
        float e1 = __expf(sf[i][1] + bf2f(bl[(j + 1) >> 3][(j + 1) & 7]));
        float e2 = __expf(sf[i][2] + bf2f(bl[(j + 2) >> 3][(j + 2) & 7]));
        float e3 = __expf(sf[i][3] + bf2f(bl[(j + 3) >> 3][(j + 3) & 7]));
        s24 += (e0 + e1) + (e2 + e3);
        pq[i].x = f2bf(e0); pq[i].y = f2bf(e1); pq[i].z = f2bf(e2); pq[i].w = f2bf(e3);
    }
    s24 += __shfl_xor(s24, 16);
    s24 += __shfl_xor(s24, 32);
    if (g == 0) red[w][n15] = s24;

    #pragma unroll
    for (int i = 0; i < 6; ++i)
        *reinterpret_cast<ushort4*>(&Pl[n15 * 200 + w * 96 + i * 16 + g * 4]) = pq[i];
    __syncthreads();

    // ---- PV swapped: D[ch][tok] = mfma(A=V^T, B=P~) ----
    f32x4 oacc = f32x4{0.f, 0.f, 0.f, 0.f};
    #pragma unroll
    for (int ks = 0; ks < 6; ++ks) {
        bf16x8 vf = ld_bf8(&VT[(w * 16 + n15) * 200 + ks * 32 + g * 8]);
        bf16x8 pa = ld_bf8(&Pl[n15 * 200 + ks * 32 + g * 8]);
        oacc = __builtin_amdgcn_mfma_f32_16x16x32_bf16(vf, pa, oacc, 0, 0, 0);
    }
    // lane n15 = token (col), rows g*4..g*4+3 = channels w*16+g*4..+3
    {
        float inv = 1.f / (red[0][n15] + red[1][n15]);
        int gtr = d * 2304 + (y0 + (n15 >> 2)) * 48 + (x0 + (n15 & 3));
        ushort4 o;
        o.x = f2bf(oacc[0] * inv);
        o.y = f2bf(oacc[1] * inv);
        o.z = f2bf(oacc[2] * inv);
        o.w = f2bf(oacc[3] * inv);
        *reinterpret_cast<ushort4*>(aout + (size_t)gtr * 256 + h * 32 + w * 16 + g * 4) = o;
    }
}

extern "C" void kernel_launch(void* const* d_in, const int* in_sizes, int n_in,
                              void* d_out, int out_size, void* d_ws, size_t ws_size,
                              hipStream_t stream) {
    const float* x      = (const float*)d_in[0];
    const float* w_qkv  = (const float*)d_in[1];
    const float* b_qkv  = (const float*)d_in[2];
    const float* rpb    = (const float*)d_in[3];
    const float* w_proj = (const float*)d_in[4];
    const float* b_proj = (const float*)d_in[5];
    float* out = (float*)d_out;

    unsigned short* ws = (unsigned short*)d_ws;
    unsigned short* xb    = ws;                       // 2359296
    unsigned short* wqT   = ws + (size_t)2359296;     // 196608
    unsigned short* wpT   = ws + (size_t)2555904;     // 65536
    unsigned short* qws   = ws + (size_t)2621440;     // 2359296
    unsigned short* kws   = ws + (size_t)4980736;     // 2359296
    unsigned short* vws   = ws + (size_t)7340032;     // 2359296
    unsigned short* aws   = ws + (size_t)9699328;     // 2359296
    unsigned short* biasT = ws + (size_t)12058624;    // 884736

    conv_prep<<<dim3(3616), 256, 0, stream>>>(x, w_qkv, w_proj, rpb, xb, wqT, wpT, biasT);

    // QKV: [9216,256] x [256,768] ; block tile 128x128
    gemm_mfma<4, 4, 0><<<dim3(6, 72), 256, 0, stream>>>(xb, wqT, b_qkv, qws, kws, vws, nullptr);

    nat_attn_mfma<<<dim3(4608), 128, 0, stream>>>(qws, kws, vws, biasT, aws);

    // proj: [9216,256] x [256,256] ; block tile 64x64
    gemm_mfma<2, 2, 1><<<dim3(4, 144), 256, 0, stream>>>(aws, wpT, b_proj, nullptr, nullptr, nullptr, out);
}

// Round 10
// 64.609 us; speedup vs baseline: 1.0476x; 1.0167x over previous
//
#include <hip/hip_runtime.h>

#define QK_SCALE 0.17677669529663687f  // 32^-0.5
#define TOKENS 9216

typedef __attribute__((ext_vector_type(8))) __bf16 bf16x8;
typedef __attribute__((ext_vector_type(8))) unsigned short us8;
typedef __attribute__((ext_vector_type(4))) float f32x4;

static __device__ __forceinline__ unsigned short f2bf(float x) {
    unsigned int u = __float_as_uint(x);
    return (unsigned short)((u + 0x7FFFu + ((u >> 16) & 1u)) >> 16);
}
static __device__ __forceinline__ float bf2f(unsigned short u) {
    return __uint_as_float(((unsigned int)u) << 16);
}
static __device__ __forceinline__ bf16x8 ld_bf8(const unsigned short* p) {
    us8 u = *reinterpret_cast<const us8*>(p);
    return __builtin_bit_cast(bf16x8, u);
}

// ---------- fused prep: x->bf16; w_qkv->bf16 T [768][256]; w_proj->bf16 T [256][256];
//            bias table 36 cls x 8 heads x [tok:16][w:2][g:4][j:24], j=i*4+rg -> cand=w*96+i*16+g*4+rg
__global__ __launch_bounds__(256) void conv_prep(
    const float* __restrict__ x, const float* __restrict__ wqkv, const float* __restrict__ wproj,
    const float* __restrict__ rpb,
    unsigned short* __restrict__ xb, unsigned short* __restrict__ wqT,
    unsigned short* __restrict__ wpT, unsigned short* __restrict__ biasT)
{
    int b = blockIdx.x, t = threadIdx.x;
    if (b < 2304) {
        int idx = (b * 256 + t) * 4;
        float4 v = *reinterpret_cast<const float4*>(x + idx);
        ushort4 o;
        o.x = f2bf(v.x); o.y = f2bf(v.y); o.z = f2bf(v.z); o.w = f2bf(v.w);
        *reinterpret_cast<ushort4*>(xb + idx) = o;
    } else if (b < 3072) {
        int e = (b - 2304) * 256 + t;      // 768*256
        int n = e >> 8, k = e & 255;
        wqT[n * 256 + k] = f2bf(wqkv[k * 768 + n]);
    } else if (b < 3328) {
        int e = (b - 3072) * 256 + t;      // 256*256
        int n = e >> 8, k = e & 255;
        wpT[n * 256 + k] = f2bf(wproj[k * 256 + n]);
    } else {
        const int bid = b - 3328;          // cls*8 + h
        const int cls = bid >> 3, h = bid & 7;
        const int d  = cls / 9;
        const int r  = cls % 9;
        const int yc = r / 3, xc = r % 3;
        const int by = (yc == 0) ? 0 : ((yc == 1) ? 5 : 11);
        const int bx = (xc == 0) ? 0 : ((xc == 1) ? 5 : 11);
        const int y0 = by * 4, x0 = bx * 4;
        const int base_d = min(max(d - 1, 0), 1);
        const int base_h = min(max(y0 - 2, 0), 40);
        const int base_w = min(max(x0 - 2, 0), 40);
        const int relD = base_d - d + 2;
        unsigned short* dst = biasT + (size_t)bid * 3072;
        for (int idx = t; idx < 3072; idx += 256) {
            // idx = ((tok*2 + w)*4 + g)*24 + j ; j = i*4 + rg
            int tok = idx / 192;
            int rem = idx - tok * 192;
            int w = rem / 96; rem -= w * 96;
            int g = rem / 24;
            int j = rem - g * 24;
            int i = j >> 2, rg = j & 3;
            int cand = w * 96 + i * 16 + g * 4 + rg;
            int y = y0 + (tok >> 2), xx = x0 + (tok & 3);
            int sh = min(max(y - 2, 0), 43), sw = min(max(xx - 2, 0), 43);
            int ld = cand >> 6, lh = (cand >> 3) & 7, lw = cand & 7;
            int t0 = lh - (sh - base_h), t1 = lw - (sw - base_w);
            bool valid = ((unsigned)t0 < 5u) && ((unsigned)t1 < 5u);
            unsigned short v = 0xFF80;  // bf16 -inf
            if (valid) {
                int bi = (relD + ld) * 81 + (lh - (y - base_h) + 4) * 9 + (lw - (xx - base_w) + 4);
                v = f2bf(rpb[h * 405 + bi]);
            }
            dst[idx] = v;
        }
    }
}

// ---------- LDS-free MFMA GEMM: C[M][N] = A[M][256] * BT[N][256]^T, K=256
// Swapped operands: acc = mfma(b, a) -> D col(n15)=token row m, reg quad = 4 consecutive n.
// MODE 0: qkv epilogue, ushort4 stores (4 consecutive channels) into [head][token][32]
// MODE 1: float4 stores into [token][N]
template<int MF, int NF, int MODE>
__global__ __launch_bounds__(256) void gemm_mfma(
    const unsigned short* __restrict__ A, const unsigned short* __restrict__ BT,
    const float* __restrict__ bias,
    unsigned short* __restrict__ oq, unsigned short* __restrict__ ok,
    unsigned short* __restrict__ ov, float* __restrict__ of)
{
    const int tid = threadIdx.x;
    const int wid = tid >> 6, lane = tid & 63;
    const int wm = wid >> 1, wn = wid & 1;
    const int n15 = lane & 15, g = lane >> 4;
    const int m0 = blockIdx.y * (MF * 32) + wm * (MF * 16);
    const int n0 = blockIdx.x * (NF * 32) + wn * (NF * 16);

    f32x4 acc[MF][NF];
    #pragma unroll
    for (int i = 0; i < MF; i++)
        #pragma unroll
        for (int j = 0; j < NF; j++)
            acc[i][j] = f32x4{0.f, 0.f, 0.f, 0.f};

    #pragma unroll
    for (int ks = 0; ks < 8; ++ks) {
        bf16x8 a[MF], b[NF];
        #pragma unroll
        for (int mt = 0; mt < MF; ++mt)
            a[mt] = ld_bf8(A + (size_t)(m0 + mt * 16 + n15) * 256 + ks * 32 + g * 8);
        #pragma unroll
        for (int nt = 0; nt < NF; ++nt)
            b[nt] = ld_bf8(BT + (size_t)(n0 + nt * 16 + n15) * 256 + ks * 32 + g * 8);
        #pragma unroll
        for (int mt = 0; mt < MF; ++mt)
            #pragma unroll
            for (int nt = 0; nt < NF; ++nt)
                acc[mt][nt] = __builtin_amdgcn_mfma_f32_16x16x32_bf16(b[nt], a[mt], acc[mt][nt], 0, 0, 0);
    }

    #pragma unroll
    for (int mt = 0; mt < MF; ++mt) {
        #pragma unroll
        for (int nt = 0; nt < NF; ++nt) {
            int tok = m0 + mt * 16 + n15;
            int nb  = n0 + nt * 16 + g * 4;
            float4 bv4 = *reinterpret_cast<const float4*>(bias + nb);
            float v0 = acc[mt][nt][0] + bv4.x;
            float v1 = acc[mt][nt][1] + bv4.y;
            float v2 = acc[mt][nt][2] + bv4.z;
            float v3 = acc[mt][nt][3] + bv4.w;
            if (MODE == 0) {
                int part = nb >> 8, c = nb & 255, hh = c >> 5, ch = c & 31;
                unsigned short* dst = (part == 0) ? oq : ((part == 1) ? ok : ov);
                if (part == 0) { v0 *= QK_SCALE; v1 *= QK_SCALE; v2 *= QK_SCALE; v3 *= QK_SCALE; }
                ushort4 o;
                o.x = f2bf(v0); o.y = f2bf(v1); o.z = f2bf(v2); o.w = f2bf(v3);
                *reinterpret_cast<ushort4*>(dst + ((size_t)hh * TOKENS + tok) * 32 + ch) = o;
            } else {
                float4 o = make_float4(v0, v1, v2, v3);
                *reinterpret_cast<float4*>(of + (size_t)tok * 256 + nb) = o;
            }
        }
    }
}

// ---------- MFMA neighborhood attention ----------
// block: 1 head x 4x4x1 token tile (16 tokens), candidate union = 3x8x8 = 192; 2 waves.
// Swapped QK^T: mfma(K,Q) -> lane n15 = token, regs = 24 cands. Max-free softmax fully
// in-lane (2 shuffles), P~ truncated-packed (uint2). PV swapped: mfma(V^T,P) -> D[ch][tok],
// one reciprocal + one ushort4 store per thread. Normalization deferred to epilogue.
__global__ __launch_bounds__(128) void nat_attn_mfma(
    const unsigned short* __restrict__ qws, const unsigned short* __restrict__ kws,
    const unsigned short* __restrict__ vws, const unsigned short* __restrict__ biasT,
    unsigned short* __restrict__ aout)
{
    __shared__ unsigned short VT[32 * 200];   // V^T [ch][cand], stride 200
    __shared__ unsigned short Pl[16 * 200];   // P~  [tok][cand], stride 200
    __shared__ float red[2][16];              // per-wave partial denominators

    const int tid = threadIdx.x;
    const int w = tid >> 6, lane = tid & 63;
    const int n15 = lane & 15, g = lane >> 4;

    int b = blockIdx.x;
    const int h = b & 7; b >>= 3;
    const int bx = b % 12; b /= 12;
    const int by = b % 12;
    const int d  = b / 12;
    const int y0 = by * 4, x0 = bx * 4;
    const int base_d = min(max(d - 1, 0), 1);
    const int base_h = min(max(y0 - 2, 0), 40);
    const int base_w = min(max(x0 - 2, 0), 40);

    const int yc = (by == 0) ? 0 : ((by == 11) ? 2 : 1);
    const int xc = (bx == 0) ? 0 : ((bx == 11) ? 2 : 1);
    const unsigned short* bT = biasT + (size_t)(((d * 9 + yc * 3 + xc) * 8 + h)) * 3072;

    const size_t hoff = (size_t)h * TOKENS * 32;
    const unsigned short* kb = kws + hoff;
    const unsigned short* vb = vws + hoff;
    const unsigned short* qb = qws + hoff;

    // ---- stage V^T (coalesced global reads, scalar LDS transpose writes) ----
    for (int id = tid; id < 768; id += 128) {
        int cand = id % 192, chg = id / 192;
        int ld = cand >> 6, lh = (cand >> 3) & 7, lw = cand & 7;
        int gt = (base_d + ld) * 2304 + (base_h + lh) * 48 + (base_w + lw);
        us8 u = *reinterpret_cast<const us8*>(vb + (size_t)gt * 32 + chg * 8);
        #pragma unroll
        for (int e = 0; e < 8; e++) VT[(chg * 8 + e) * 200 + cand] = u[e];
    }

    // ---- bias loads: 24 contiguous bf16 per lane = 3 x us8 ----
    us8 bl[3];
    {
        const unsigned short* bp = bT + (size_t)(((n15 * 2 + w) * 4 + g) * 24);
        bl[0] = *reinterpret_cast<const us8*>(bp);
        bl[1] = *reinterpret_cast<const us8*>(bp + 8);
        bl[2] = *reinterpret_cast<const us8*>(bp + 16);
    }

    // ---- QK^T (swapped: A=K, B=Q) -> D[cand][tok], lane n15 = token ----
    const int gtq = d * 2304 + (y0 + (n15 >> 2)) * 48 + (x0 + (n15 & 3));
    bf16x8 qf = ld_bf8(qb + (size_t)gtq * 32 + g * 8);

    f32x4 sf[6];
    #pragma unroll
    for (int i = 0; i < 6; ++i) {
        int cand = (w * 6 + i) * 16 + n15;
        int ld = cand >> 6, lh = (cand >> 3) & 7, lw = cand & 7;
        int gtc = (base_d + ld) * 2304 + (base_h + lh) * 48 + (base_w + lw);
        bf16x8 kf = ld_bf8(kb + (size_t)gtc * 32 + g * 8);
        sf[i] = __builtin_amdgcn_mfma_f32_16x16x32_bf16(kf, qf, f32x4{0.f, 0.f, 0.f, 0.f}, 0, 0, 0);
    }

    // ---- max-free softmax, fully in-lane; cand = w*96 + i*16 + g*4 + rg, tok = n15 ----
    // P~ packed by truncation (positive values; denominator uses the same truncated
    // values' f32 originals -> common-mode rounding cancels after normalization)
    float s24 = 0.f;
    uint2 pq[6];
    #pragma unroll
    for (int i = 0; i < 6; ++i) {
        int j = i * 4;
        float e0 = __expf(sf[i][0] + bf2f(bl[(j + 0) >> 3][(j + 0) & 7]));
        float e1 = __expf(sf[i][1] + bf2f(bl[(j + 1) >> 3][(j + 1) & 7]));
        float e2 = __expf(sf[i][2] + bf2f(bl[(j + 2) >> 3][(j + 2) & 7]));
        float e3 = __expf(sf[i][3] + bf2f(bl[(j + 3) >> 3][(j + 3) & 7]));
        s24 += (e0 + e1) + (e2 + e3);
        pq[i].x = (__float_as_uint(e1) & 0xFFFF0000u) | (__float_as_uint(e0) >> 16);
        pq[i].y = (__float_as_uint(e3) & 0xFFFF0000u) | (__float_as_uint(e2) >> 16);
    }
    s24 += __shfl_xor(s24, 16);
    s24 += __shfl_xor(s24, 32);
    if (g == 0) red[w][n15] = s24;

    #pragma unroll
    for (int i = 0; i < 6; ++i)
        *reinterpret_cast<uint2*>(&Pl[n15 * 200 + w * 96 + i * 16 + g * 4]) = pq[i];
    __syncthreads();

    // ---- PV swapped: D[ch][tok] = mfma(A=V^T, B=P~) ----
    f32x4 oacc = f32x4{0.f, 0.f, 0.f, 0.f};
    #pragma unroll
    for (int ks = 0; ks < 6; ++ks) {
        bf16x8 vf = ld_bf8(&VT[(w * 16 + n15) * 200 + ks * 32 + g * 8]);
        bf16x8 pa = ld_bf8(&Pl[n15 * 200 + ks * 32 + g * 8]);
        oacc = __builtin_amdgcn_mfma_f32_16x16x32_bf16(vf, pa, oacc, 0, 0, 0);
    }
    // lane n15 = token (col), rows g*4..g*4+3 = channels w*16+g*4..+3
    {
        float inv = 1.f / (red[0][n15] + red[1][n15]);
        int gtr = d * 2304 + (y0 + (n15 >> 2)) * 48 + (x0 + (n15 & 3));
        ushort4 o;
        o.x = f2bf(oacc[0] * inv);
        o.y = f2bf(oacc[1] * inv);
        o.z = f2bf(oacc[2] * inv);
        o.w = f2bf(oacc[3] * inv);
        *reinterpret_cast<ushort4*>(aout + (size_t)gtr * 256 + h * 32 + w * 16 + g * 4) = o;
    }
}

extern "C" void kernel_launch(void* const* d_in, const int* in_sizes, int n_in,
                              void* d_out, int out_size, void* d_ws, size_t ws_size,
                              hipStream_t stream) {
    const float* x      = (const float*)d_in[0];
    const float* w_qkv  = (const float*)d_in[1];
    const float* b_qkv  = (const float*)d_in[2];
    const float* rpb    = (const float*)d_in[3];
    const float* w_proj = (const float*)d_in[4];
    const float* b_proj = (const float*)d_in[5];
    float* out = (float*)d_out;

    unsigned short* ws = (unsigned short*)d_ws;
    unsigned short* xb    = ws;                       // 2359296
    unsigned short* wqT   = ws + (size_t)2359296;     // 196608
    unsigned short* wpT   = ws + (size_t)2555904;     // 65536
    unsigned short* qws   = ws + (size_t)2621440;     // 2359296
    unsigned short* kws   = ws + (size_t)4980736;     // 2359296
    unsigned short* vws   = ws + (size_t)7340032;     // 2359296
    unsigned short* aws   = ws + (size_t)9699328;     // 2359296
    unsigned short* biasT = ws + (size_t)12058624;    // 884736

    conv_prep<<<dim3(3616), 256, 0, stream>>>(x, w_qkv, w_proj, rpb, xb, wqT, wpT, biasT);

    // QKV: [9216,256] x [256,768] ; block tile 128x128
    gemm_mfma<4, 4, 0><<<dim3(6, 72), 256, 0, stream>>>(xb, wqT, b_qkv, qws, kws, vws, nullptr);

    nat_attn_mfma<<<dim3(4608), 128, 0, stream>>>(qws, kws, vws, biasT, aws);

    // proj: [9216,256] x [256,256] ; block tile 64x64
    gemm_mfma<2, 2, 1><<<dim3(4, 144), 256, 0, stream>>>(aws, wpT, b_proj, nullptr, nullptr, nullptr, out);
}